// Round 1
// baseline (148.661 us; speedup 1.0000x reference)
//
#include <hip/hip_runtime.h>
#include <hip/hip_bf16.h>

// Instant-NGP style hash grid interpolation.
// x: [N, 3] f32 in [0,1), emb: [524288, 8] f32, out: [N, 8] f32.

#define HASHMAP_MASK 524287u   // 2^19 - 1
#define RESOLUTION   128.0f
#define PRIME1       2654435761u
#define PRIME2       805459861u

__global__ __launch_bounds__(256) void hashgrid_kernel(
    const float* __restrict__ x,
    const float* __restrict__ emb,
    float* __restrict__ out,
    int n)
{
    int i = blockIdx.x * blockDim.x + threadIdx.x;
    if (i >= n) return;

    // Load the 3 coords (wave reads 768 contiguous bytes -> coalesced).
    float x0 = x[i * 3 + 0];
    float x1 = x[i * 3 + 1];
    float x2 = x[i * 3 + 2];

    float xr0 = x0 * RESOLUTION;
    float xr1 = x1 * RESOLUTION;
    float xr2 = x2 * RESOLUTION;

    float fl0 = floorf(xr0);
    float fl1 = floorf(xr1);
    float fl2 = floorf(xr2);

    // fractional parts (exact: xr - floor(xr))
    float f0 = xr0 - fl0;
    float f1 = xr1 - fl1;
    float f2 = xr2 - fl2;

    unsigned u0 = (unsigned)(int)fl0;
    unsigned u1 = (unsigned)(int)fl1;
    unsigned u2 = (unsigned)(int)fl2;

    // Precompute hash terms for base and +1 in each dim (uint32 wraparound).
    unsigned h0a = u0 * 1u,      h0b = (u0 + 1u) * 1u;
    unsigned h1a = u1 * PRIME1,  h1b = (u1 + 1u) * PRIME1;
    unsigned h2a = u2 * PRIME2,  h2b = (u2 + 1u) * PRIME2;

    float g0 = 1.0f - f0;
    float g1 = 1.0f - f1;
    float g2 = 1.0f - f2;

    float acc0 = 0.f, acc1 = 0.f, acc2 = 0.f, acc3 = 0.f;
    float acc4 = 0.f, acc5 = 0.f, acc6 = 0.f, acc7 = 0.f;

#pragma unroll
    for (int c = 0; c < 8; ++c) {
        unsigned t0 = (c & 1) ? h0b : h0a;
        unsigned t1 = (c & 2) ? h1b : h1a;
        unsigned t2 = (c & 4) ? h2b : h2a;
        unsigned h = (t0 ^ t1 ^ t2) & HASHMAP_MASK;

        float w = ((c & 1) ? f0 : g0) *
                  ((c & 2) ? f1 : g1) *
                  ((c & 4) ? f2 : g2);

        const float4* e = reinterpret_cast<const float4*>(emb + (size_t)h * 8u);
        float4 e0 = e[0];
        float4 e1 = e[1];

        acc0 += w * e0.x; acc1 += w * e0.y; acc2 += w * e0.z; acc3 += w * e0.w;
        acc4 += w * e1.x; acc5 += w * e1.y; acc6 += w * e1.z; acc7 += w * e1.w;
    }

    float4* o = reinterpret_cast<float4*>(out + (size_t)i * 8u);
    o[0] = make_float4(acc0, acc1, acc2, acc3);
    o[1] = make_float4(acc4, acc5, acc6, acc7);
}

extern "C" void kernel_launch(void* const* d_in, const int* in_sizes, int n_in,
                              void* d_out, int out_size, void* d_ws, size_t ws_size,
                              hipStream_t stream) {
    const float* x   = (const float*)d_in[0];
    const float* emb = (const float*)d_in[1];
    float* out = (float*)d_out;

    int n = in_sizes[0] / 3;  // x has N*3 elements
    int block = 256;
    int grid = (n + block - 1) / block;
    hashgrid_kernel<<<grid, block, 0, stream>>>(x, emb, out, n);
}